// Round 17
// baseline (452.452 us; speedup 1.0000x reference)
//
#include <hip/hip_runtime.h>
#include <cstdint>
#include <cstddef>

#define DEVINL __device__ __forceinline__

typedef __attribute__((ext_vector_type(8))) short short8;
typedef __attribute__((ext_vector_type(4))) float f32x4;
typedef unsigned short u16;
typedef unsigned int u32;

// ---------- bf16 helpers (RNE) ----------
DEVINL u16 f2b(float f) {
    u32 u = __float_as_uint(f);
    u32 r = (u + 0x7fffu + ((u >> 16) & 1u)) >> 16;
    return (u16)r;
}
DEVINL float b2f(u16 h) { return __uint_as_float(((u32)h) << 16); }

DEVINL void gl_lds16(const void* g, void* l) {
    __builtin_amdgcn_global_load_lds(
        (const __attribute__((address_space(1))) void*)g,
        (__attribute__((address_space(3))) void*)l, 16, 0, 0);
}

// ---------- constants ----------
#define MROWS   25096
#define NTOK    3137
#define QE      25698304
#define LOG2E   1.4426950408889634f
#define SCL2    0.1803368801111204f   /* 0.125 * log2(e) */

// ---------- fp32 -> bf16 conversion ----------
__global__ __launch_bounds__(256) void cvt_kernel(const float* __restrict__ in,
                                                  u16* __restrict__ out, int n4) {
    int i = blockIdx.x * blockDim.x + threadIdx.x;
    int stride = gridDim.x * blockDim.x;
    for (int j = i; j < n4; j += stride) {
        float4 v = ((const float4*)in)[j];
        ushort4 o;
        o.x = f2b(v.x); o.y = f2b(v.y); o.z = f2b(v.z); o.w = f2b(v.w);
        ((ushort4*)out)[j] = o;
    }
}

// ================= 256x256 bf16 MFMA GEMM, early-stage rotated pipeline ================
// Round-11 base (rotated frag pre-reads) with stages moved to p1+p2 so every vmcnt
// covers loads >=2 phases (~780+ cyc) old vs HBM ~900 cyc:
//  p1: rd a4(cb,k0) ; STAGE A(nb,k0)+B(nb,k0) ; MFMA(ra,rb,0) ; vmcnt(4) [cb k1: prev p2] ; bar
//  p2: rd c0,d0(cb,k1); STAGE A(nb,k1)+B(nb,k1); MFMA(a4,rb,4)                            ; bar
//  p3: rd e4(cb,k1)  ;                           MFMA(c0,d0,0); vmcnt(4) [nb k0: this p1] ; bar
//  p4: rd ra,rb(nb,k0);                          MFMA(e4,d0,4)                            ; bar
// Steady-state queue: enter 4 -> p1 +4 =8, vmcnt(4) -> p2 +4 =8 -> p3 vmcnt(4) -> p4 -> 4.
// nb write-safe at p1: its last reads were prev tile's p3, two barriers back.

#define LDS_BUF 32768
#define NTILES  16

template <int MODE>
__global__ __launch_bounds__(512, 2) void gemm256(const u16* __restrict__ A,
                                                  const u16* __restrict__ B,
                                                  u16* __restrict__ q_out,
                                                  u16* __restrict__ k_out,
                                                  u16* __restrict__ v_out,
                                                  const float* __restrict__ bias,
                                                  float* __restrict__ f_out, int M) {
    __shared__ u16 lds[2 * LDS_BUF];   // 128 KiB
    const int tid = threadIdx.x, lane = tid & 63, w = tid >> 6;
    const int Mm1 = M - 1;

    const u32 nwg = gridDim.x * gridDim.y;
    const u32 orig = blockIdx.y * gridDim.x + blockIdx.x;
    const u32 q8 = nwg >> 3, r8 = nwg & 7, xcd = orig & 7, rest = orig >> 3;
    const u32 wg = (xcd < r8 ? xcd * (q8 + 1) : r8 * (q8 + 1) + (xcd - r8) * q8) + rest;
    const int m0 = (int)(wg / gridDim.x) * 256;
    const int n0 = (int)(wg % gridDim.x) * 256;

    const int wm = w >> 2, wn = w & 3;

    const int stRow = lane >> 2;
    const int stCol = (((lane & 3) ^ ((lane >> 3) & 3)) << 3);

    const int slotOff = (((lane >> 4) ^ ((lane >> 1) & 3)) << 3);
    const int rdA = (wm * 128 + (lane & 15)) * 32 + slotOff;
    const int rdB = (wn * 64 + (lane & 15)) * 32 + slotOff + 16384;

#define STAGE_A(NB, KK, KT) do {                                              \
    _Pragma("unroll") for (int j_ = 0; j_ < 2; ++j_) {                        \
        const int c_ = (w << 1) | j_;                                         \
        int r_ = m0 + c_ * 16 + stRow; if (r_ > Mm1) r_ = Mm1;                \
        gl_lds16(A + (size_t)r_ * 1024 + (KT) + (KK) * 32 + stCol,            \
                 lds + (NB) + (KK) * 8192 + c_ * 512);                        \
    } } while (0)

#define STAGE_B(NB, KK, KT) do {                                              \
    _Pragma("unroll") for (int j_ = 0; j_ < 2; ++j_) {                        \
        const int c_ = (w << 1) | j_;                                         \
        const int r_ = n0 + c_ * 16 + stRow;                                  \
        gl_lds16(B + (size_t)r_ * 1024 + (KT) + (KK) * 32 + stCol,            \
                 lds + (NB) + 16384 + (KK) * 8192 + c_ * 512);                \
    } } while (0)

#define LDA4(DST, CB, KK, MB) do {                                            \
    _Pragma("unroll") for (int i_ = 0; i_ < 4; ++i_)                          \
        DST[i_] = *(const short8*)&lds[(CB) + (KK) * 8192 + rdA +             \
                                       ((MB) + i_) * 16 * 32];                \
    } while (0)

#define LDB4(DST, CB, KK) do {                                                \
    _Pragma("unroll") for (int i_ = 0; i_ < 4; ++i_)                          \
        DST[i_] = *(const short8*)&lds[(CB) + (KK) * 8192 + rdB +             \
                                       i_ * 16 * 32];                         \
    } while (0)

#define MFMA16(AV, BV, MB) do {                                               \
    _Pragma("unroll") for (int i_ = 0; i_ < 4; ++i_)                          \
        _Pragma("unroll") for (int n_ = 0; n_ < 4; ++n_)                      \
            acc[(MB) + i_][n_] = __builtin_amdgcn_mfma_f32_16x16x32_bf16(     \
                AV[i_], BV[n_], acc[(MB) + i_][n_], 0, 0, 0);                 \
    } while (0)

#define VMW(N) do {                                                           \
    asm volatile("s_waitcnt vmcnt(" #N ")" ::: "memory");                     \
    __builtin_amdgcn_sched_barrier(0); } while (0)

#define PHASE_BAR() do {                                                      \
    __builtin_amdgcn_s_barrier();                                             \
    __builtin_amdgcn_sched_barrier(0); } while (0)

    f32x4 acc[8][4];
    const f32x4 zf = {0.f, 0.f, 0.f, 0.f};
#pragma unroll
    for (int i = 0; i < 8; ++i)
#pragma unroll
        for (int j = 0; j < 4; ++j) acc[i][j] = zf;

    // ---- prologue: stage tile 0 into buf0; prove kk0; pre-read T=0 p1 frags ----
    STAGE_A(0, 0, 0);
    STAGE_B(0, 0, 0);
    STAGE_A(0, 1, 0);
    STAGE_B(0, 1, 0);
    VMW(4);            // completes kk0 A+B; kk1 A+B (4 loads) outstanding
    PHASE_BAR();

    short8 ra[4], rb[4];
    LDA4(ra, 0, 0, 0);
    LDB4(rb, 0, 0);

    for (int T = 0; T < NTILES; ++T) {
        const int cb = (T & 1) * LDS_BUF;
        const int nb = ((T + 1) & 1) * LDS_BUF;
        const bool pf = (T < NTILES - 1);
        const int kt1 = (T + 1) * 64;

        short8 a4[4], c0[4], d0[4], e4[4];

        // ---- phase 1: MFMA kk0 m0-3 ; stage nb k0 (A+B) ----
        LDA4(a4, cb, 0, 4);
        if (pf) { STAGE_A(nb, 0, kt1); STAGE_B(nb, 0, kt1); }
        __builtin_amdgcn_s_setprio(1);
        MFMA16(ra, rb, 0);
        __builtin_amdgcn_s_setprio(0);
        if (pf) { VMW(4); }   // completes cb kk1 A+B (issued prev p2, 3 phases back)
        else    { VMW(0); }
        PHASE_BAR();

        // ---- phase 2: MFMA kk0 m4-7 ; stage nb k1 (A+B) ----
        LDA4(c0, cb, 1, 0);
        LDB4(d0, cb, 1);
        if (pf) { STAGE_A(nb, 1, kt1); STAGE_B(nb, 1, kt1); }
        __builtin_amdgcn_s_setprio(1);
        MFMA16(a4, rb, 4);
        __builtin_amdgcn_s_setprio(0);
        PHASE_BAR();

        // ---- phase 3: MFMA kk1 m0-3 ----
        LDA4(e4, cb, 1, 4);
        __builtin_amdgcn_s_setprio(1);
        MFMA16(c0, d0, 0);
        __builtin_amdgcn_s_setprio(0);
        if (pf) { VMW(4); }   // completes nb kk0 A+B (issued this p1, 2 phases back)
        PHASE_BAR();

        // ---- phase 4: MFMA kk1 m4-7 ; pre-read next tile's p1 frags from nb ----
        if (pf) {
            LDA4(ra, nb, 0, 0);
            LDB4(rb, nb, 0);
        }
        __builtin_amdgcn_s_setprio(1);
        MFMA16(e4, d0, 4);
        __builtin_amdgcn_s_setprio(0);
        PHASE_BAR();
    }

    // ---- epilogue: C layout col=lane&15, row=(lane>>4)*4+reg ----
#pragma unroll
    for (int m = 0; m < 8; ++m) {
#pragma unroll
        for (int n = 0; n < 4; ++n) {
#pragma unroll
            for (int r = 0; r < 4; ++r) {
                const int gm = m0 + wm * 128 + m * 16 + ((lane >> 4) << 2) + r;
                if (gm < M) {
                    const int gc = n0 + wn * 64 + n * 16 + (lane & 15);
                    if (MODE == 0) {
                        const int t = gc >> 10;
                        const int h = (gc >> 6) & 15;
                        const int d = gc & 63;
                        const u32 bb = (u32)gm / 3137u;
                        const u32 nn = (u32)gm - bb * 3137u;
                        u16* dst = (t == 0) ? q_out : (t == 1) ? k_out : v_out;
                        dst[(((size_t)(bb * 16 + h)) * NTOK + nn) * 64 + d] =
                            f2b(acc[m][n][r]);
                    } else {
                        f_out[(size_t)gm * 1024 + gc] = acc[m][n][r] + bias[gc];
                    }
                }
            }
        }
    }
#undef STAGE_A
#undef STAGE_B
#undef LDA4
#undef LDB4
#undef MFMA16
#undef VMW
#undef PHASE_BAR
}

// ---------- cls attention, split-K flash ----------
#define CSZ 393
__global__ __launch_bounds__(256) void attn_cls_part(const u16* __restrict__ qb,
                                                     const u16* __restrict__ kb,
                                                     const u16* __restrict__ vb,
                                                     float* __restrict__ part) {
    const int bid = blockIdx.x;
    const int bh = bid >> 3, c = bid & 7;
    const size_t base = (size_t)bh * NTOK * 64;
    const int tid = threadIdx.x, lane = tid & 63, wid = tid >> 6;
    const int j0 = c * CSZ;
    const int cnt = min(NTOK - j0, CSZ);

    __shared__ float qs[64];
    __shared__ float sc[CSZ];
    __shared__ float redbuf[8];
    __shared__ float ored[4][64];

    if (tid < 64) qs[tid] = b2f(qb[base + tid]);
    __syncthreads();

    for (int j = tid; j < cnt; j += 256) {
        const u16* kr = kb + base + (size_t)(j0 + j) * 64;
        float acc = 0.f;
#pragma unroll
        for (int c2 = 0; c2 < 8; ++c2) {
            short8 v8 = *(const short8*)(kr + c2 * 8);
#pragma unroll
            for (int t = 0; t < 8; ++t) acc += qs[c2 * 8 + t] * b2f((u16)v8[t]);
        }
        sc[j] = acc * 0.125f;
    }
    __syncthreads();

    float mx = -1e30f;
    for (int j = tid; j < cnt; j += 256) mx = fmaxf(mx, sc[j]);
#pragma unroll
    for (int m = 32; m >= 1; m >>= 1) mx = fmaxf(mx, __shfl_xor(mx, m));
    if (lane == 0) redbuf[wid] = mx;
    __syncthreads();
    mx = fmaxf(fmaxf(redbuf[0], redbuf[1]), fmaxf(redbuf[2], redbuf[3]));

    float sum = 0.f;
    for (int j = tid; j < cnt; j += 256) {
        float p = exp2f((sc[j] - mx) * LOG2E);
        sc[j] = p;
        sum += p;
    }
#pragma unroll
    for (int m = 32; m >= 1; m >>= 1) sum += __shfl_xor(sum, m);
    if (lane == 0) redbuf[4 + wid] = sum;
    __syncthreads();
    const float tot = redbuf[4] + redbuf[5] + redbuf[6] + redbuf[7];

    const int d = tid & 63, g = tid >> 6;
    float o = 0.f;
    for (int j = g; j < cnt; j += 4)
        o += sc[j] * b2f(vb[base + (size_t)(j0 + j) * 64 + d]);
    ored[g][d] = o;
    __syncthreads();

    float* pb = part + (size_t)bid * 66;
    if (tid < 64) pb[2 + tid] = ored[0][tid] + ored[1][tid] + ored[2][tid] + ored[3][tid];
    else if (tid == 64) pb[0] = mx;
    else if (tid == 65) pb[1] = tot;
}

__global__ __launch_bounds__(64) void attn_cls_fin(const float* __restrict__ part,
                                                   u16* __restrict__ attnb) {
    const int bh = blockIdx.x, d = threadIdx.x;
    const int bb = bh >> 4, h = bh & 15;
    float m = -1e30f;
#pragma unroll
    for (int c = 0; c < 8; ++c) m = fmaxf(m, part[(size_t)(bh * 8 + c) * 66]);
    float t = 0.f, o = 0.f;
#pragma unroll
    for (int c = 0; c < 8; ++c) {
        const float* pb = part + (size_t)(bh * 8 + c) * 66;
        const float w = exp2f((pb[0] - m) * LOG2E);
        t += w * pb[1];
        o += w * pb[2 + d];
    }
    attnb[(size_t)bb * NTOK * 1024 + h * 64 + d] = f2b(o / t);
}

// ---------- spatial attention: swapped-QK, in-register unnormalized P (verified) ----
__global__ __launch_bounds__(256, 3) void attn_spatial(const u16* __restrict__ qb,
                                                       const u16* __restrict__ kb,
                                                       const u16* __restrict__ vb,
                                                       u16* __restrict__ attnb) {
    const int blk = blockIdx.x;
    const int bh = blk >> 4, fi = blk & 15;
    const int bb = bh >> 4, h = bh & 15;
    const int tid = threadIdx.x, lane = tid & 63, wid = tid >> 6;
    const int hi = lane >> 4, lo = lane & 15;
    const size_t kvbase = (size_t)bh * NTOK * 64;

    __shared__ u16 Kl[208 * 64];   // XOR-swizzled K rows (197 real + 11 zero)
    __shared__ u16 Vt[64 * 208];   // V transposed, stride 208 (pad cols zero)

    const short8 z8 = {0, 0, 0, 0, 0, 0, 0, 0};

    for (int idx = tid; idx < 208 * 8; idx += 256) {
        const int j = idx >> 3, c = idx & 7;
        short8 kval = z8;
        if (j < 197) {
            const int n = (j == 0) ? 0 : (1 + fi * 196 + (j - 1));
            kval = *(const short8*)(kb + kvbase + (size_t)n * 64 + c * 8);
            const short8 v8 = *(const short8*)(vb + kvbase + (size_t)n * 64 + c * 8);
#pragma unroll
            for (int t0 = 0; t0 < 8; ++t0) {
                const int t = (t0 + c) & 7;
                Vt[(c * 8 + t) * 208 + j] = (u16)v8[t];
            }
        } else {
#pragma unroll
            for (int t = 0; t < 8; ++t) Vt[(c * 8 + t) * 208 + j] = 0;
        }
        *(short8*)(Kl + ((j * 64 + c * 8) ^ ((j & 7) << 3))) = kval;
    }
    __syncthreads();

    const int ksw = (lo & 7) << 3;
    const int src0 = lo + ((hi & 1) << 5);
    const int src1 = src0 + 16;
    const f32x4 zf = {0.f, 0.f, 0.f, 0.f};

    for (int mf = wid; mf < 13; mf += 4) {
        int qr = mf * 16 + lo; if (qr > 195) qr = 195;
        const u16* qp = qb + kvbase + (size_t)(1 + fi * 196 + qr) * 64 + hi * 8;
        const short8 qb0 = *(const short8*)(qp);
        const short8 qb1 = *(const short8*)(qp + 32);

        f32x4 s[13];
#pragma unroll
        for (int nf = 0; nf < 13; ++nf) s[nf] = zf;
#pragma unroll
        for (int nf = 0; nf < 13; ++nf) {
            const int e0 = (nf * 16 + lo) * 64 + hi * 8;
            const short8 a0 = *(const short8*)(Kl + (e0 ^ ksw));
            const short8 a1 = *(const short8*)(Kl + ((e0 + 32) ^ ksw));
            s[nf] = __builtin_amdgcn_mfma_f32_16x16x32_bf16(a0, qb0, s[nf], 0, 0, 0);
            s[nf] = __builtin_amdgcn_mfma_f32_16x16x32_bf16(a1, qb1, s[nf], 0, 0, 0);
        }

        float mx = s[0][0];
#pragma unroll
        for (int nf = 0; nf < 13; ++nf)
#pragma unroll
            for (int reg = 0; reg < 4; ++reg) mx = fmaxf(mx, s[nf][reg]);
        mx = fmaxf(mx, __shfl_xor(mx, 16));
        mx = fmaxf(mx, __shfl_xor(mx, 32));
        const float mC = mx * SCL2;
        float sum = 0.f;
#pragma unroll
        for (int nf = 0; nf < 13; ++nf)
#pragma unroll
            for (int reg = 0; reg < 4; ++reg) {
                const float p = exp2f(fmaf(s[nf][reg], SCL2, -mC));
                s[nf][reg] = p;
                sum += p;
            }
        sum += __shfl_xor(sum, 16);
        sum += __shfl_xor(sum, 32);
        const float rls = 1.0f / (sum - 11.0f * exp2f(-mC));

        // pack UNNORMALIZED P (values in [0,1])
        u32 w0[13], w1[13];
#pragma unroll
        for (int nf = 0; nf < 13; ++nf) {
            asm("v_cvt_pk_bf16_f32 %0, %1, %2"
                : "=v"(w0[nf]) : "v"(s[nf][0]), "v"(s[nf][1]));
            asm("v_cvt_pk_bf16_f32 %0, %1, %2"
                : "=v"(w1[nf]) : "v"(s[nf][2]), "v"(s[nf][3]));
        }

        f32x4 o[4];
#pragma unroll
        for (int i = 0; i < 4; ++i) o[i] = zf;
#pragma unroll
        for (int kk = 0; kk < 7; ++kk) {
            u32 x0, x1, x2, x3;
            if (kk < 6) {
                const u32 aA0 = __shfl(w0[2 * kk], src0), aA1 = __shfl(w1[2 * kk], src0);
                const u32 aA2 = __shfl(w0[2 * kk], src1), aA3 = __shfl(w1[2 * kk], src1);
                const u32 aB0 = __shfl(w0[2 * kk + 1], src0), aB1 = __shfl(w1[2 * kk + 1], src0);
                const u32 aB2 = __shfl(w0[2 * kk + 1], src1), aB3 = __shfl(w1[2 * kk + 1], src1);
                const bool lh = hi < 2;
                x0 = lh ? aA0 : aB0; x1 = lh ? aA1 : aB1;
                x2 = lh ? aA2 : aB2; x3 = lh ? aA3 : aB3;
            } else {
                const u32 aA0 = __shfl(w0[12], src0), aA1 = __shfl(w1[12], src0);
                const u32 aA2 = __shfl(w0[12], src1), aA3 = __shfl(w1[12], src1);
                const bool lh = hi < 2;
                x0 = lh ? aA0 : 0u; x1 = lh ? aA1 : 0u;
                x2 = lh ? aA2 : 0u; x3 = lh ? aA3 : 0u;
            }
            union { u32 u[4]; short8 v; } pu;
            pu.u[0] = x0; pu.u[1] = x1; pu.u[2] = x2; pu.u[3] = x3;
            const short8 pa = pu.v;
#pragma unroll
            for (int nf2 = 0; nf2 < 4; ++nf2) {
                short8 bv = z8;
                if (kk < 6 || hi < 2)
                    bv = *(const short8*)(Vt + (nf2 * 16 + lo) * 208 + kk * 32 + hi * 8);
                o[nf2] = __builtin_amdgcn_mfma_f32_16x16x32_bf16(pa, bv, o[nf2], 0, 0, 0);
            }
        }

        // epilogue: O row q = mf*16 + 4hi + reg needs rls of q' = 4hi+reg (lane q' holds it)
        float rr[4];
#pragma unroll
        for (int reg = 0; reg < 4; ++reg) rr[reg] = __shfl(rls, hi * 4 + reg);
#pragma unroll
        for (int nf2 = 0; nf2 < 4; ++nf2)
#pragma unroll
            for (int reg = 0; reg < 4; ++reg) {
                const int r = mf * 16 + hi * 4 + reg;
                if (r < 196) {
                    const int d = nf2 * 16 + lo;
                    const size_t nn = 1 + fi * 196 + r;
                    attnb[((size_t)bb * NTOK + nn) * 1024 + h * 64 + d] =
                        f2b(o[nf2][reg] * rr[reg]);
                }
            }
    }
}

// ---------- launch ----------
extern "C" void kernel_launch(void* const* d_in, const int* in_sizes, int n_in,
                              void* d_out, int out_size, void* d_ws, size_t ws_size,
                              hipStream_t stream) {
    const float* x = (const float*)d_in[0];
    const float* w_qkv = (const float*)d_in[1];
    const float* w_out = (const float*)d_in[2];
    const float* b_out = (const float*)d_in[3];

    const size_t need = ((size_t)QE * 2 + 3145728 + 1048576) * 2;
    if (ws_size < need) {
        hipMemsetAsync(d_out, 0, (size_t)out_size * 4, stream);
        return;
    }

    u16* vb = (u16*)d_ws;
    u16* xab = vb + QE;
    u16* wqb = xab + QE;
    u16* wob = wqb + 3145728;
    u16* qb = (u16*)d_out;
    u16* kb = qb + QE;
    float* outf = (float*)d_out;
    float* clsp = (float*)wqb;

    cvt_kernel<<<2048, 256, 0, stream>>>(x, xab, QE / 4);
    cvt_kernel<<<2048, 256, 0, stream>>>(w_qkv, wqb, 3145728 / 4);
    cvt_kernel<<<1024, 256, 0, stream>>>(w_out, wob, 1048576 / 4);

    gemm256<0><<<dim3(12, 99), 512, 0, stream>>>(xab, wqb, qb, kb, vb, nullptr,
                                                 nullptr, MROWS);
    attn_cls_part<<<1024, 256, 0, stream>>>(qb, kb, vb, clsp);
    attn_cls_fin<<<128, 64, 0, stream>>>(clsp, xab);
    attn_spatial<<<2048, 256, 0, stream>>>(qb, kb, vb, xab);
    gemm256<1><<<dim3(4, 99), 512, 0, stream>>>(xab, wob, nullptr, nullptr, nullptr,
                                                b_out, outf, MROWS);
}

// Round 18
// 445.325 us; speedup vs baseline: 1.0160x; 1.0160x over previous
//
#include <hip/hip_runtime.h>
#include <cstdint>
#include <cstddef>

#define DEVINL __device__ __forceinline__

typedef __attribute__((ext_vector_type(8))) short short8;
typedef __attribute__((ext_vector_type(4))) float f32x4;
typedef unsigned short u16;
typedef unsigned int u32;

// ---------- bf16 helpers (RNE) ----------
DEVINL u16 f2b(float f) {
    u32 u = __float_as_uint(f);
    u32 r = (u + 0x7fffu + ((u >> 16) & 1u)) >> 16;
    return (u16)r;
}
DEVINL float b2f(u16 h) { return __uint_as_float(((u32)h) << 16); }

DEVINL void gl_lds16(const void* g, void* l) {
    __builtin_amdgcn_global_load_lds(
        (const __attribute__((address_space(1))) void*)g,
        (__attribute__((address_space(3))) void*)l, 16, 0, 0);
}

// ---------- constants ----------
#define MROWS   25096
#define NTOK    3137
#define QE      25698304
#define LOG2E   1.4426950408889634f
#define SCL2    0.1803368801111204f   /* 0.125 * log2(e) */

// ---------- fp32 -> bf16 conversion ----------
__global__ __launch_bounds__(256) void cvt_kernel(const float* __restrict__ in,
                                                  u16* __restrict__ out, int n4) {
    int i = blockIdx.x * blockDim.x + threadIdx.x;
    int stride = gridDim.x * blockDim.x;
    for (int j = i; j < n4; j += stride) {
        float4 v = ((const float4*)in)[j];
        ushort4 o;
        o.x = f2b(v.x); o.y = f2b(v.y); o.z = f2b(v.z); o.w = f2b(v.w);
        ((ushort4*)out)[j] = o;
    }
}

// ================= 256x256 bf16 MFMA GEMM, fully-rotated read-ahead pipeline ===========
// FINAL verified schedule (round-11/16, 447.6-451.8 us across 3 runs).
// A row-major [M][1024], B = [N][1024] (B^T). K = 1024, NT = 16 K-tiles.
// 512 threads = 8 waves (2M x 4N). LDS: 2 bufs x (A[2][256][32]+B[2][256][32]) = 128 KiB.
// T2 slot swizzle (phys_slot = log ^ ((row>>1)&3); source pre-swizzled) -> 0 bank conflicts.
// Rotated read-ahead: every phase's MFMA operands are ds_read one phase earlier (p4
// pre-reads next tile's p1 frags from nb). vmcnt accounting (2 loads per STAGE):
//  p1: +STAGE_A(nb,k0) -> queue [cbA1,cbB1,nbA0]=6 ; vmcnt(2) completes cbA1+cbB1
//  p3: +STAGE_A(nb,k1) -> queue [nbA0,nbB0,nbA1]=6 ; vmcnt(2) completes nbA0+nbB0
// Settled experiments: bunching stages into fewer phases regresses (r6, r17);
// vmcnt(4) here races (r10); 32x32 frags re-introduce LDS conflicts (r5).

#define LDS_BUF 32768
#define NTILES  16

template <int MODE>
__global__ __launch_bounds__(512, 2) void gemm256(const u16* __restrict__ A,
                                                  const u16* __restrict__ B,
                                                  u16* __restrict__ q_out,
                                                  u16* __restrict__ k_out,
                                                  u16* __restrict__ v_out,
                                                  const float* __restrict__ bias,
                                                  float* __restrict__ f_out, int M) {
    __shared__ u16 lds[2 * LDS_BUF];   // 128 KiB
    const int tid = threadIdx.x, lane = tid & 63, w = tid >> 6;
    const int Mm1 = M - 1;

    const u32 nwg = gridDim.x * gridDim.y;
    const u32 orig = blockIdx.y * gridDim.x + blockIdx.x;
    const u32 q8 = nwg >> 3, r8 = nwg & 7, xcd = orig & 7, rest = orig >> 3;
    const u32 wg = (xcd < r8 ? xcd * (q8 + 1) : r8 * (q8 + 1) + (xcd - r8) * q8) + rest;
    const int m0 = (int)(wg / gridDim.x) * 256;
    const int n0 = (int)(wg % gridDim.x) * 256;

    const int wm = w >> 2, wn = w & 3;

    const int stRow = lane >> 2;
    const int stCol = (((lane & 3) ^ ((lane >> 3) & 3)) << 3);

    const int slotOff = (((lane >> 4) ^ ((lane >> 1) & 3)) << 3);
    const int rdA = (wm * 128 + (lane & 15)) * 32 + slotOff;
    const int rdB = (wn * 64 + (lane & 15)) * 32 + slotOff + 16384;

#define STAGE_A(NB, KK, KT) do {                                              \
    _Pragma("unroll") for (int j_ = 0; j_ < 2; ++j_) {                        \
        const int c_ = (w << 1) | j_;                                         \
        int r_ = m0 + c_ * 16 + stRow; if (r_ > Mm1) r_ = Mm1;                \
        gl_lds16(A + (size_t)r_ * 1024 + (KT) + (KK) * 32 + stCol,            \
                 lds + (NB) + (KK) * 8192 + c_ * 512);                        \
    } } while (0)

#define STAGE_B(NB, KK, KT) do {                                              \
    _Pragma("unroll") for (int j_ = 0; j_ < 2; ++j_) {                        \
        const int c_ = (w << 1) | j_;                                         \
        const int r_ = n0 + c_ * 16 + stRow;                                  \
        gl_lds16(B + (size_t)r_ * 1024 + (KT) + (KK) * 32 + stCol,            \
                 lds + (NB) + 16384 + (KK) * 8192 + c_ * 512);                \
    } } while (0)

#define LDA4(DST, CB, KK, MB) do {                                            \
    _Pragma("unroll") for (int i_ = 0; i_ < 4; ++i_)                          \
        DST[i_] = *(const short8*)&lds[(CB) + (KK) * 8192 + rdA +             \
                                       ((MB) + i_) * 16 * 32];                \
    } while (0)

#define LDB4(DST, CB, KK) do {                                                \
    _Pragma("unroll") for (int i_ = 0; i_ < 4; ++i_)                          \
        DST[i_] = *(const short8*)&lds[(CB) + (KK) * 8192 + rdB +             \
                                       i_ * 16 * 32];                         \
    } while (0)

#define MFMA16(AV, BV, MB) do {                                               \
    _Pragma("unroll") for (int i_ = 0; i_ < 4; ++i_)                          \
        _Pragma("unroll") for (int n_ = 0; n_ < 4; ++n_)                      \
            acc[(MB) + i_][n_] = __builtin_amdgcn_mfma_f32_16x16x32_bf16(     \
                AV[i_], BV[n_], acc[(MB) + i_][n_], 0, 0, 0);                 \
    } while (0)

#define VMW(N) do {                                                           \
    asm volatile("s_waitcnt vmcnt(" #N ")" ::: "memory");                     \
    __builtin_amdgcn_sched_barrier(0); } while (0)

#define PHASE_BAR() do {                                                      \
    __builtin_amdgcn_s_barrier();                                             \
    __builtin_amdgcn_sched_barrier(0); } while (0)

    f32x4 acc[8][4];
    const f32x4 zf = {0.f, 0.f, 0.f, 0.f};
#pragma unroll
    for (int i = 0; i < 8; ++i)
#pragma unroll
        for (int j = 0; j < 4; ++j) acc[i][j] = zf;

    // ---- prologue: stage tile 0 into buf0; prove kk0; pre-read T=0 p1 frags ----
    STAGE_A(0, 0, 0);
    STAGE_B(0, 0, 0);
    STAGE_A(0, 1, 0);
    STAGE_B(0, 1, 0);
    VMW(4);            // completes kk0 A+B; kk1 A+B (4) outstanding
    PHASE_BAR();

    short8 ra[4], rb[4];
    LDA4(ra, 0, 0, 0);
    LDB4(rb, 0, 0);

    for (int T = 0; T < NTILES; ++T) {
        const int cb = (T & 1) * LDS_BUF;
        const int nb = ((T + 1) & 1) * LDS_BUF;
        const bool pf = (T < NTILES - 1);
        const int kt1 = (T + 1) * 64;

        short8 a4[4], c0[4], d0[4], e4[4];

        // ---- phase 1: MFMA kk0 m0-3 (ra,rb) ; read-ahead kk0 m4-7 ----
        LDA4(a4, cb, 0, 4);
        if (pf) STAGE_A(nb, 0, kt1);
        __builtin_amdgcn_s_setprio(1);
        MFMA16(ra, rb, 0);
        __builtin_amdgcn_s_setprio(0);
        if (pf) { VMW(2); }   // completes cb kk1 A+B (staged prev p3+p4)
        else    { VMW(0); }
        PHASE_BAR();

        // ---- phase 2: MFMA kk0 m4-7 ; read-ahead kk1 m0-3 + Bk1 ----
        LDA4(c0, cb, 1, 0);
        LDB4(d0, cb, 1);
        if (pf) STAGE_B(nb, 0, kt1);
        __builtin_amdgcn_s_setprio(1);
        MFMA16(a4, rb, 4);
        __builtin_amdgcn_s_setprio(0);
        PHASE_BAR();

        // ---- phase 3: MFMA kk1 m0-3 ; read-ahead kk1 m4-7 ----
        LDA4(e4, cb, 1, 4);
        if (pf) STAGE_A(nb, 1, kt1);
        __builtin_amdgcn_s_setprio(1);
        MFMA16(c0, d0, 0);
        __builtin_amdgcn_s_setprio(0);
        if (pf) { VMW(2); }   // completes nb kk0 A+B (staged this p1+p2)
        PHASE_BAR();

        // ---- phase 4: MFMA kk1 m4-7 ; pre-read next tile's p1 frags from nb ----
        if (pf) {
            LDA4(ra, nb, 0, 0);
            LDB4(rb, nb, 0);
            STAGE_B(nb, 1, kt1);
        }
        __builtin_amdgcn_s_setprio(1);
        MFMA16(e4, d0, 4);
        __builtin_amdgcn_s_setprio(0);
        PHASE_BAR();
    }

    // ---- epilogue: C layout col=lane&15, row=(lane>>4)*4+reg ----
#pragma unroll
    for (int m = 0; m < 8; ++m) {
#pragma unroll
        for (int n = 0; n < 4; ++n) {
#pragma unroll
            for (int r = 0; r < 4; ++r) {
                const int gm = m0 + wm * 128 + m * 16 + ((lane >> 4) << 2) + r;
                if (gm < M) {
                    const int gc = n0 + wn * 64 + n * 16 + (lane & 15);
                    if (MODE == 0) {
                        const int t = gc >> 10;
                        const int h = (gc >> 6) & 15;
                        const int d = gc & 63;
                        const u32 bb = (u32)gm / 3137u;
                        const u32 nn = (u32)gm - bb * 3137u;
                        u16* dst = (t == 0) ? q_out : (t == 1) ? k_out : v_out;
                        dst[(((size_t)(bb * 16 + h)) * NTOK + nn) * 64 + d] =
                            f2b(acc[m][n][r]);
                    } else {
                        f_out[(size_t)gm * 1024 + gc] = acc[m][n][r] + bias[gc];
                    }
                }
            }
        }
    }
#undef STAGE_A
#undef STAGE_B
#undef LDA4
#undef LDB4
#undef MFMA16
#undef VMW
#undef PHASE_BAR
}

// ---------- cls attention, split-K flash ----------
#define CSZ 393
__global__ __launch_bounds__(256) void attn_cls_part(const u16* __restrict__ qb,
                                                     const u16* __restrict__ kb,
                                                     const u16* __restrict__ vb,
                                                     float* __restrict__ part) {
    const int bid = blockIdx.x;
    const int bh = bid >> 3, c = bid & 7;
    const size_t base = (size_t)bh * NTOK * 64;
    const int tid = threadIdx.x, lane = tid & 63, wid = tid >> 6;
    const int j0 = c * CSZ;
    const int cnt = min(NTOK - j0, CSZ);

    __shared__ float qs[64];
    __shared__ float sc[CSZ];
    __shared__ float redbuf[8];
    __shared__ float ored[4][64];

    if (tid < 64) qs[tid] = b2f(qb[base + tid]);
    __syncthreads();

    for (int j = tid; j < cnt; j += 256) {
        const u16* kr = kb + base + (size_t)(j0 + j) * 64;
        float acc = 0.f;
#pragma unroll
        for (int c2 = 0; c2 < 8; ++c2) {
            short8 v8 = *(const short8*)(kr + c2 * 8);
#pragma unroll
            for (int t = 0; t < 8; ++t) acc += qs[c2 * 8 + t] * b2f((u16)v8[t]);
        }
        sc[j] = acc * 0.125f;
    }
    __syncthreads();

    float mx = -1e30f;
    for (int j = tid; j < cnt; j += 256) mx = fmaxf(mx, sc[j]);
#pragma unroll
    for (int m = 32; m >= 1; m >>= 1) mx = fmaxf(mx, __shfl_xor(mx, m));
    if (lane == 0) redbuf[wid] = mx;
    __syncthreads();
    mx = fmaxf(fmaxf(redbuf[0], redbuf[1]), fmaxf(redbuf[2], redbuf[3]));

    float sum = 0.f;
    for (int j = tid; j < cnt; j += 256) {
        float p = exp2f((sc[j] - mx) * LOG2E);
        sc[j] = p;
        sum += p;
    }
#pragma unroll
    for (int m = 32; m >= 1; m >>= 1) sum += __shfl_xor(sum, m);
    if (lane == 0) redbuf[4 + wid] = sum;
    __syncthreads();
    const float tot = redbuf[4] + redbuf[5] + redbuf[6] + redbuf[7];

    const int d = tid & 63, g = tid >> 6;
    float o = 0.f;
    for (int j = g; j < cnt; j += 4)
        o += sc[j] * b2f(vb[base + (size_t)(j0 + j) * 64 + d]);
    ored[g][d] = o;
    __syncthreads();

    float* pb = part + (size_t)bid * 66;
    if (tid < 64) pb[2 + tid] = ored[0][tid] + ored[1][tid] + ored[2][tid] + ored[3][tid];
    else if (tid == 64) pb[0] = mx;
    else if (tid == 65) pb[1] = tot;
}

__global__ __launch_bounds__(64) void attn_cls_fin(const float* __restrict__ part,
                                                   u16* __restrict__ attnb) {
    const int bh = blockIdx.x, d = threadIdx.x;
    const int bb = bh >> 4, h = bh & 15;
    float m = -1e30f;
#pragma unroll
    for (int c = 0; c < 8; ++c) m = fmaxf(m, part[(size_t)(bh * 8 + c) * 66]);
    float t = 0.f, o = 0.f;
#pragma unroll
    for (int c = 0; c < 8; ++c) {
        const float* pb = part + (size_t)(bh * 8 + c) * 66;
        const float w = exp2f((pb[0] - m) * LOG2E);
        t += w * pb[1];
        o += w * pb[2 + d];
    }
    attnb[(size_t)bb * NTOK * 1024 + h * 64 + d] = f2b(o / t);
}

// ---------- spatial attention: swapped-QK, in-register unnormalized P (verified) ----
// 256 threads, launch_bounds(256,3): VGPR 84, no spill, 3 blocks/CU. Best measured.
// Settled: 512-thread variants spill under any launch_bounds (r14/r15); K-from-L2
// thrashes per-XCD L2 at scale (r12); softmax tree-reduction neutral (r13).
__global__ __launch_bounds__(256, 3) void attn_spatial(const u16* __restrict__ qb,
                                                       const u16* __restrict__ kb,
                                                       const u16* __restrict__ vb,
                                                       u16* __restrict__ attnb) {
    const int blk = blockIdx.x;
    const int bh = blk >> 4, fi = blk & 15;
    const int bb = bh >> 4, h = bh & 15;
    const int tid = threadIdx.x, lane = tid & 63, wid = tid >> 6;
    const int hi = lane >> 4, lo = lane & 15;
    const size_t kvbase = (size_t)bh * NTOK * 64;

    __shared__ u16 Kl[208 * 64];   // XOR-swizzled K rows (197 real + 11 zero)
    __shared__ u16 Vt[64 * 208];   // V transposed, stride 208 (pad cols zero)

    const short8 z8 = {0, 0, 0, 0, 0, 0, 0, 0};

    for (int idx = tid; idx < 208 * 8; idx += 256) {
        const int j = idx >> 3, c = idx & 7;
        short8 kval = z8;
        if (j < 197) {
            const int n = (j == 0) ? 0 : (1 + fi * 196 + (j - 1));
            kval = *(const short8*)(kb + kvbase + (size_t)n * 64 + c * 8);
            const short8 v8 = *(const short8*)(vb + kvbase + (size_t)n * 64 + c * 8);
#pragma unroll
            for (int t0 = 0; t0 < 8; ++t0) {
                const int t = (t0 + c) & 7;
                Vt[(c * 8 + t) * 208 + j] = (u16)v8[t];
            }
        } else {
#pragma unroll
            for (int t = 0; t < 8; ++t) Vt[(c * 8 + t) * 208 + j] = 0;
        }
        *(short8*)(Kl + ((j * 64 + c * 8) ^ ((j & 7) << 3))) = kval;
    }
    __syncthreads();

    const int ksw = (lo & 7) << 3;
    const int src0 = lo + ((hi & 1) << 5);
    const int src1 = src0 + 16;
    const f32x4 zf = {0.f, 0.f, 0.f, 0.f};

    for (int mf = wid; mf < 13; mf += 4) {
        int qr = mf * 16 + lo; if (qr > 195) qr = 195;
        const u16* qp = qb + kvbase + (size_t)(1 + fi * 196 + qr) * 64 + hi * 8;
        const short8 qb0 = *(const short8*)(qp);
        const short8 qb1 = *(const short8*)(qp + 32);

        f32x4 s[13];
#pragma unroll
        for (int nf = 0; nf < 13; ++nf) s[nf] = zf;
#pragma unroll
        for (int nf = 0; nf < 13; ++nf) {
            const int e0 = (nf * 16 + lo) * 64 + hi * 8;
            const short8 a0 = *(const short8*)(Kl + (e0 ^ ksw));
            const short8 a1 = *(const short8*)(Kl + ((e0 + 32) ^ ksw));
            s[nf] = __builtin_amdgcn_mfma_f32_16x16x32_bf16(a0, qb0, s[nf], 0, 0, 0);
            s[nf] = __builtin_amdgcn_mfma_f32_16x16x32_bf16(a1, qb1, s[nf], 0, 0, 0);
        }

        float mx = s[0][0];
#pragma unroll
        for (int nf = 0; nf < 13; ++nf)
#pragma unroll
            for (int reg = 0; reg < 4; ++reg) mx = fmaxf(mx, s[nf][reg]);
        mx = fmaxf(mx, __shfl_xor(mx, 16));
        mx = fmaxf(mx, __shfl_xor(mx, 32));
        const float mC = mx * SCL2;
        float sum = 0.f;
#pragma unroll
        for (int nf = 0; nf < 13; ++nf)
#pragma unroll
            for (int reg = 0; reg < 4; ++reg) {
                const float p = exp2f(fmaf(s[nf][reg], SCL2, -mC));
                s[nf][reg] = p;
                sum += p;
            }
        sum += __shfl_xor(sum, 16);
        sum += __shfl_xor(sum, 32);
        const float rls = 1.0f / (sum - 11.0f * exp2f(-mC));

        // pack UNNORMALIZED P (values in [0,1])
        u32 w0[13], w1[13];
#pragma unroll
        for (int nf = 0; nf < 13; ++nf) {
            asm("v_cvt_pk_bf16_f32 %0, %1, %2"
                : "=v"(w0[nf]) : "v"(s[nf][0]), "v"(s[nf][1]));
            asm("v_cvt_pk_bf16_f32 %0, %1, %2"
                : "=v"(w1[nf]) : "v"(s[nf][2]), "v"(s[nf][3]));
        }

        f32x4 o[4];
#pragma unroll
        for (int i = 0; i < 4; ++i) o[i] = zf;
#pragma unroll
        for (int kk = 0; kk < 7; ++kk) {
            u32 x0, x1, x2, x3;
            if (kk < 6) {
                const u32 aA0 = __shfl(w0[2 * kk], src0), aA1 = __shfl(w1[2 * kk], src0);
                const u32 aA2 = __shfl(w0[2 * kk], src1), aA3 = __shfl(w1[2 * kk], src1);
                const u32 aB0 = __shfl(w0[2 * kk + 1], src0), aB1 = __shfl(w1[2 * kk + 1], src0);
                const u32 aB2 = __shfl(w0[2 * kk + 1], src1), aB3 = __shfl(w1[2 * kk + 1], src1);
                const bool lh = hi < 2;
                x0 = lh ? aA0 : aB0; x1 = lh ? aA1 : aB1;
                x2 = lh ? aA2 : aB2; x3 = lh ? aA3 : aB3;
            } else {
                const u32 aA0 = __shfl(w0[12], src0), aA1 = __shfl(w1[12], src0);
                const u32 aA2 = __shfl(w0[12], src1), aA3 = __shfl(w1[12], src1);
                const bool lh = hi < 2;
                x0 = lh ? aA0 : 0u; x1 = lh ? aA1 : 0u;
                x2 = lh ? aA2 : 0u; x3 = lh ? aA3 : 0u;
            }
            union { u32 u[4]; short8 v; } pu;
            pu.u[0] = x0; pu.u[1] = x1; pu.u[2] = x2; pu.u[3] = x3;
            const short8 pa = pu.v;
#pragma unroll
            for (int nf2 = 0; nf2 < 4; ++nf2) {
                short8 bv = z8;
                if (kk < 6 || hi < 2)
                    bv = *(const short8*)(Vt + (nf2 * 16 + lo) * 208 + kk * 32 + hi * 8);
                o[nf2] = __builtin_amdgcn_mfma_f32_16x16x32_bf16(pa, bv, o[nf2], 0, 0, 0);
            }
        }

        // epilogue: O row q = mf*16 + 4hi + reg needs rls of q' = 4hi+reg (lane q' holds it)
        float rr[4];
#pragma unroll
        for (int reg = 0; reg < 4; ++reg) rr[reg] = __shfl(rls, hi * 4 + reg);
#pragma unroll
        for (int nf2 = 0; nf2 < 4; ++nf2)
#pragma unroll
            for (int reg = 0; reg < 4; ++reg) {
                const int r = mf * 16 + hi * 4 + reg;
                if (r < 196) {
                    const int d = nf2 * 16 + lo;
                    const size_t nn = 1 + fi * 196 + r;
                    attnb[((size_t)bb * NTOK + nn) * 1024 + h * 64 + d] =
                        f2b(o[nf2][reg] * rr[reg]);
                }
            }
    }
}

// ---------- launch ----------
extern "C" void kernel_launch(void* const* d_in, const int* in_sizes, int n_in,
                              void* d_out, int out_size, void* d_ws, size_t ws_size,
                              hipStream_t stream) {
    const float* x = (const float*)d_in[0];
    const float* w_qkv = (const float*)d_in[1];
    const float* w_out = (const float*)d_in[2];
    const float* b_out = (const float*)d_in[3];

    const size_t need = ((size_t)QE * 2 + 3145728 + 1048576) * 2;
    if (ws_size < need) {
        hipMemsetAsync(d_out, 0, (size_t)out_size * 4, stream);
        return;
    }

    u16* vb = (u16*)d_ws;
    u16* xab = vb + QE;
    u16* wqb = xab + QE;
    u16* wob = wqb + 3145728;
    u16* qb = (u16*)d_out;
    u16* kb = qb + QE;
    float* outf = (float*)d_out;
    float* clsp = (float*)wqb;

    cvt_kernel<<<2048, 256, 0, stream>>>(x, xab, QE / 4);
    cvt_kernel<<<2048, 256, 0, stream>>>(w_qkv, wqb, 3145728 / 4);
    cvt_kernel<<<1024, 256, 0, stream>>>(w_out, wob, 1048576 / 4);

    gemm256<0><<<dim3(12, 99), 512, 0, stream>>>(xab, wqb, qb, kb, vb, nullptr,
                                                 nullptr, MROWS);
    attn_cls_part<<<1024, 256, 0, stream>>>(qb, kb, vb, clsp);
    attn_cls_fin<<<128, 64, 0, stream>>>(clsp, xab);
    attn_spatial<<<2048, 256, 0, stream>>>(qb, kb, vb, xab);
    gemm256<1><<<dim3(4, 99), 512, 0, stream>>>(xab, wob, nullptr, nullptr, nullptr,
                                                b_out, outf, MROWS);
}